// Round 1
// baseline (748.890 us; speedup 1.0000x reference)
//
#include <hip/hip_runtime.h>

// ---------------- types / helpers ----------------
typedef __bf16        bf16x8 __attribute__((ext_vector_type(8)));
typedef float         f32x4  __attribute__((ext_vector_type(4)));

typedef unsigned int __attribute__((address_space(1))) as1_u32;
typedef unsigned int __attribute__((address_space(3))) as3_u32;
#define ASYNC16(gp, lp) __builtin_amdgcn_global_load_lds((as1_u32*)(gp), (as3_u32*)(lp), 16, 0, 0)

#define SCALE_F 0.07216878364870323f      /* 192^-0.5 */
#define LOG2E_F 1.4426950408889634f
#define FQ (SCALE_F * LOG2E_F)            /* folded into Q so softmax is exp2 */

static __device__ __forceinline__ unsigned short f2bf(float f) {
  unsigned int u = __builtin_bit_cast(unsigned int, f);
  u += 0x7fff + ((u >> 16) & 1);          // RNE
  return (unsigned short)(u >> 16);
}
static __device__ __forceinline__ float bf2f(unsigned short s) {
  unsigned int u = ((unsigned int)s) << 16;
  return __builtin_bit_cast(float, u);
}

// ---------------- fp32 -> bf16 convert ----------------
__global__ __launch_bounds__(256) void k_f2b(const float* __restrict__ in,
                                             unsigned short* __restrict__ out, int n) {
  int stride = gridDim.x * 256;
  for (int i = blockIdx.x * 256 + threadIdx.x; i < n; i += stride) out[i] = f2bf(in[i]);
}

// wkv_b (16,256,512) -> w_nt[h][c][d] (nope slice transposed) and w_v[h][d][c] (v slice)
__global__ __launch_bounds__(256) void k_wkvb(const float* __restrict__ wkvb,
                                              unsigned short* __restrict__ w_nt,
                                              unsigned short* __restrict__ w_v) {
  int i = blockIdx.x * 256 + threadIdx.x;      // 0 .. 16*512*128-1
  int h = i >> 16;
  int rem = i & 65535;
  int c = rem >> 7, d = rem & 127;             // for w_nt
  w_nt[i] = f2bf(wkvb[((h << 8) + d) * 512 + c]);
  int d2 = rem >> 9, c2 = rem & 511;           // for w_v
  w_v[i] = f2bf(wkvb[((h << 8) + 128 + d2) * 512 + c2]);
}

// ---------------- generic bf16 MFMA GEMM: C[M,N] = A[M,K] @ W[N,K]^T ----------------
// 128x128 tile, BK=32, 256 threads (4 waves, 2x2 of 64x64), global_load_lds staging.
template <int BF16_OUT>
__global__ __launch_bounds__(256) void k_gemm(
    const unsigned short* __restrict__ A, int lda, long long sA,
    const unsigned short* __restrict__ W, int ldw, long long sW,
    void* __restrict__ Cv, int ldc, long long sC, int K) {
  __shared__ unsigned short lA[128 * 32];
  __shared__ unsigned short lW[128 * 32];
  const int tid = threadIdx.x;
  const int lane = tid & 63;
  const int q4 = lane >> 4, c16 = lane & 15;
  const int wave = tid >> 6;
  const int wr = (wave >> 1) * 64, wc = (wave & 1) * 64;
  const int z = blockIdx.z;
  A += (long long)z * sA;
  W += (long long)z * sW;

  f32x4 acc[4][4];
#pragma unroll
  for (int i = 0; i < 4; i++)
#pragma unroll
    for (int j = 0; j < 4; j++) acc[i][j] = (f32x4)0.0f;

  const int r = tid >> 2;
  const int cc = (tid & 3) * 8;
  const unsigned short* gA0 = A + ((long long)blockIdx.y * 128 + r) * lda + cc;
  const unsigned short* gA1 = gA0 + (long long)64 * lda;
  const unsigned short* gW0 = W + ((long long)blockIdx.x * 128 + r) * ldw + cc;
  const unsigned short* gW1 = gW0 + (long long)64 * ldw;
  unsigned short* pA0 = &lA[r * 32 + cc];
  unsigned short* pA1 = &lA[(64 + r) * 32 + cc];
  unsigned short* pW0 = &lW[r * 32 + cc];
  unsigned short* pW1 = &lW[(64 + r) * 32 + cc];

  for (int k0 = 0; k0 < K; k0 += 32) {
    ASYNC16(gA0 + k0, pA0);
    ASYNC16(gA1 + k0, pA1);
    ASYNC16(gW0 + k0, pW0);
    ASYNC16(gW1 + k0, pW1);
    __syncthreads();                       // drains vmcnt -> LDS valid
    bf16x8 af[4], wf[4];
#pragma unroll
    for (int mt = 0; mt < 4; mt++)
      af[mt] = *(const bf16x8*)&lA[(wr + mt * 16 + c16) * 32 + q4 * 8];
#pragma unroll
    for (int nt = 0; nt < 4; nt++)
      wf[nt] = *(const bf16x8*)&lW[(wc + nt * 16 + c16) * 32 + q4 * 8];
#pragma unroll
    for (int mt = 0; mt < 4; mt++)
#pragma unroll
      for (int nt = 0; nt < 4; nt++)
        acc[mt][nt] = __builtin_amdgcn_mfma_f32_16x16x32_bf16(af[mt], wf[nt], acc[mt][nt], 0, 0, 0);
    __syncthreads();
  }

  const long long row0 = (long long)blockIdx.y * 128 + wr + q4 * 4;
  const int col0 = blockIdx.x * 128 + wc + c16;
  if (BF16_OUT) {
    unsigned short* C = (unsigned short*)Cv + (long long)z * sC;
#pragma unroll
    for (int mt = 0; mt < 4; mt++)
#pragma unroll
      for (int i = 0; i < 4; i++) {
        long long rr = (row0 + mt * 16 + i) * (long long)ldc + col0;
#pragma unroll
        for (int nt = 0; nt < 4; nt++) C[rr + nt * 16] = f2bf(acc[mt][nt][i]);
      }
  } else {
    float* C = (float*)Cv + (long long)z * sC;
#pragma unroll
    for (int mt = 0; mt < 4; mt++)
#pragma unroll
      for (int i = 0; i < 4; i++) {
        long long rr = (row0 + mt * 16 + i) * (long long)ldc + col0;
#pragma unroll
        for (int nt = 0; nt < 4; nt++) C[rr + nt * 16] = acc[mt][nt][i];
      }
  }
}

// ---------------- RMSNorm q_a (rows of 1536, fp32 in, bf16 out) ----------------
__global__ __launch_bounds__(256) void k_rms_q(const float* __restrict__ in,
                                               const float* __restrict__ w,
                                               unsigned short* __restrict__ out) {
  const int row = blockIdx.x;
  const int tid = threadIdx.x;
  const float* x = in + (long long)row * 1536;
  float v[6], ss = 0.f;
#pragma unroll
  for (int i = 0; i < 6; i++) { v[i] = x[tid + i * 256]; ss += v[i] * v[i]; }
#pragma unroll
  for (int d = 1; d < 64; d <<= 1) ss += __shfl_xor(ss, d);
  __shared__ float red[4];
  if ((tid & 63) == 0) red[tid >> 6] = ss;
  __syncthreads();
  float sc = rsqrtf((red[0] + red[1] + red[2] + red[3]) * (1.0f / 1536.0f) + 1e-6f);
#pragma unroll
  for (int i = 0; i < 6; i++)
    out[(long long)row * 1536 + tid + i * 256] = f2bf(v[i] * sc * w[tid + i * 256]);
}

// ---------------- kv prep: rmsnorm c(512) + rope k_pe(64) ----------------
// Outputs tile-chunk-major prepacks, contiguous 36KB/32KB per 32-t tile so the
// attention kernel can stage them with perfectly-coalesced global_load_lds:
//   kvk[b][tt][j=0..71][t'=0..31][8]  (row d-chunk major K tile,  18432 elem/tile)
//   kvt[b][tt][q=0..3][c=0..511][8]   (t'-chunk major V^T tile,   16384 elem/tile)
__global__ __launch_bounds__(256) void k_prep_kv(const float* __restrict__ kvf,
                                                 const float* __restrict__ wn,
                                                 const float* __restrict__ fc,
                                                 const float* __restrict__ fs,
                                                 unsigned short* __restrict__ kvk,
                                                 unsigned short* __restrict__ kvt) {
  const int row = blockIdx.x;          // b*2048 + t
  const int tid = threadIdx.x;
  const float* x = kvf + (long long)row * 640;
  float v0 = x[tid], v1 = x[tid + 256];
  float ss = v0 * v0 + v1 * v1;
#pragma unroll
  for (int d = 1; d < 64; d <<= 1) ss += __shfl_xor(ss, d);
  __shared__ float red[4];
  if ((tid & 63) == 0) red[tid >> 6] = ss;
  __syncthreads();
  float sc = rsqrtf((red[0] + red[1] + red[2] + red[3]) * (1.0f / 512.0f) + 1e-6f);
  const int b = row >> 11, t = row & 2047, tt = t >> 5, tl = t & 31;
  float y0 = v0 * sc * wn[tid], y1 = v1 * sc * wn[tid + 256];
  unsigned short* kb = kvk + (long long)(b * 64 + tt) * 18432;
  unsigned short* vb = kvt + (long long)(b * 64 + tt) * 16384;
  const int d0 = tid, d1 = tid + 256;
  kb[((d0 >> 3) * 32 + tl) * 8 + (d0 & 7)] = f2bf(y0);
  kb[((d1 >> 3) * 32 + tl) * 8 + (d1 & 7)] = f2bf(y1);
  vb[((tl >> 3) * 512 + d0) * 8 + (tl & 7)] = f2bf(y0);
  vb[((tl >> 3) * 512 + d1) * 8 + (tl & 7)] = f2bf(y1);
  if (tid < 32) {
    float x0 = x[512 + 2 * tid], x1 = x[513 + 2 * tid];
    float c = fc[t * 32 + tid], s = fs[t * 32 + tid];
    const int e0 = 512 + 2 * tid, e1 = e0 + 1;
    kb[((e0 >> 3) * 32 + tl) * 8 + (e0 & 7)] = f2bf(x0 * c - x1 * s);
    kb[((e1 >> 3) * 32 + tl) * 8 + (e1 & 7)] = f2bf(x0 * s + x1 * c);
  }
}

// ---------------- q repack: q[4096][3072] -> qnp[h][4096][128]*FQ, rope -> qcat[h][.][512:576]*FQ ------
__global__ __launch_bounds__(256) void k_repack(const unsigned short* __restrict__ q,
                                                const float* __restrict__ fc,
                                                const float* __restrict__ fs,
                                                unsigned short* __restrict__ qnp,
                                                unsigned short* __restrict__ qcat) {
  const int h = blockIdx.y;
  const int row = blockIdx.x * 4 + (threadIdx.x >> 6);
  const int ln = threadIdx.x & 63;
  const unsigned short* src = q + (long long)row * 3072 + h * 192;
  unsigned short* dn = qnp + ((long long)h * 4096 + row) * 128;
  dn[ln] = f2bf(bf2f(src[ln]) * FQ);
  dn[ln + 64] = f2bf(bf2f(src[ln + 64]) * FQ);
  if (ln < 32) {
    const int t = row & 2047;
    float x0 = bf2f(src[128 + 2 * ln]), x1 = bf2f(src[129 + 2 * ln]);
    float c = fc[t * 32 + ln], s = fs[t * 32 + ln];
    unsigned short* dc = qcat + ((long long)h * 4096 + row) * 576 + 512;
    dc[2 * ln] = f2bf((x0 * c - x1 * s) * FQ);
    dc[2 * ln + 1] = f2bf((x0 * s + x1 * c) * FQ);
  }
}

// ---------------- flash attention v4: M=32/wave + double-buffered pipelined staging ------
// grid (16 = {b,pair} packed for XCD-L2 affinity, 16 heads), 256 threads (4 waves x 32 q-rows
// = 128-row Q-tile). Block processes Q-tiles {p, 15-p} -> 68 T-tiles total: balanced.
// v3 was LDS-BW bound: 16 rows/wave means each 1KB K/V B-fragment feeds only 1 MFMA
// (552KB LDS reads per 128 rows ≈ 4900cyc vs 2677cyc matrix) and single-buffered staging
// serialized behind the vmcnt(0) barrier drain. v4: each B-fragment feeds 2 MFMAs
// (two 16-row A tiles -> 280KB/128rows) and next tile's global_load_lds is issued BEFORE
// the current tile's compute (2-phase pipeline, one __syncthreads per tile: its implicit
// vmcnt(0) drain lands ~3000cyc after issue = free). LDS 150KB -> 1 block/CU, 512-reg waves.
__global__ __launch_bounds__(256, 1) void k_attn(const unsigned short* __restrict__ qcat,
                                                 const unsigned short* __restrict__ kvk,
                                                 const unsigned short* __restrict__ kvt,
                                                 unsigned short* __restrict__ opk) {
  __shared__ __align__(16) unsigned short kt[2][18432];  // K tiles  [j=0..71][t'=0..31][8]
  __shared__ __align__(16) unsigned short vt[2][16384];  // V^T tiles [q=0..3][c=0..511][8]
  __shared__ __align__(16) unsigned short pl[4][32][56]; // per-wave P tile, stride 56 kills
                                                         // the 8-way write bank conflict
  const int tid = threadIdx.x, lane = tid & 63, wave = tid >> 6;
  const int q4 = lane >> 4, c16 = lane & 15;
  const int bx = blockIdx.x, h = blockIdx.y;
  const int pair = (bx & 3) | ((bx >> 3) << 2);   // 0..7
  const int b = (bx >> 2) & 1;                    // b=0 -> XCDs 0-3, b=1 -> XCDs 4-7
  const unsigned short* kvk_b = kvk + (long long)b * 64 * 18432;
  const unsigned short* kvt_b = kvt + (long long)b * 64 * 16384;

  bf16x8 ones;
#pragma unroll
  for (int i = 0; i < 8; i++) ones[i] = (__bf16)1.0f;

#define STAGE_KV(tile, buf) do {                                                             \
    const unsigned short* kg_ = kvk_b + (long long)(tile) * 18432;                           \
    const unsigned short* vg_ = kvt_b + (long long)(tile) * 16384;                           \
    _Pragma("unroll")                                                                        \
    for (int i_ = 0; i_ < 9; i_++) { int ch_ = i_ * 256 + tid; ASYNC16(kg_ + ch_ * 8, &kt[buf][ch_ * 8]); } \
    _Pragma("unroll")                                                                        \
    for (int i_ = 0; i_ < 8; i_++) { int ch_ = i_ * 256 + tid; ASYNC16(vg_ + ch_ * 8, &vt[buf][ch_ * 8]); } \
  } while (0)

  for (int seg = 0; seg < 2; seg++) {
    const int qt = seg ? (15 - pair) : pair;
    const int rbase = qt * 128 + wave * 32;                 // within-batch first q-row of wave
    const long long qrow0 = (long long)h * 4096 + b * 2048 + rbase;

    // Q fragments: 2 m-tiles x 18 k-chunks (576 dims), 144 VGPRs, reused for all 68 tiles
    bf16x8 qf[2][18];
    {
      const unsigned short* qp = qcat + (qrow0 + c16) * 576 + q4 * 8;
#pragma unroll
      for (int m = 0; m < 2; m++)
#pragma unroll
        for (int kc = 0; kc < 18; kc++)
          qf[m][kc] = *(const bf16x8*)(qp + m * 16 * 576 + kc * 32);
    }
    f32x4 oacc[2][32];
#pragma unroll
    for (int m = 0; m < 2; m++)
#pragma unroll
      for (int i = 0; i < 32; i++) oacc[m][i] = (f32x4)0.f;
    f32x4 lacc[2];
    lacc[0] = (f32x4)0.f; lacc[1] = (f32x4)0.f;

    const int nT = (qt + 1) * 4;
    STAGE_KV(0, 0);
    __syncthreads();                       // prologue drain: buf0 ready

    for (int tt = 0; tt < nT; tt++) {
      const int cur = tt & 1;
      if (tt + 1 < nT) STAGE_KV(tt + 1, cur ^ 1);   // issue-early: hides under compute
      const int t0 = tt * 32;

      // ---- S = Q K^T : each k0/k1 fragment feeds BOTH m-tiles ----
      f32x4 s[2][2];
      s[0][0] = (f32x4)0.f; s[0][1] = (f32x4)0.f; s[1][0] = (f32x4)0.f; s[1][1] = (f32x4)0.f;
      const unsigned short* ktc = kt[cur];
#pragma unroll
      for (int kc = 0; kc < 18; kc++) {
        const unsigned short* kp = &ktc[((kc * 4 + q4) * 32 + c16) * 8];
        bf16x8 k0 = *(const bf16x8*)kp;
        bf16x8 k1 = *(const bf16x8*)(kp + 128);
        s[0][0] = __builtin_amdgcn_mfma_f32_16x16x32_bf16(qf[0][kc], k0, s[0][0], 0, 0, 0);
        s[0][1] = __builtin_amdgcn_mfma_f32_16x16x32_bf16(qf[0][kc], k1, s[0][1], 0, 0, 0);
        s[1][0] = __builtin_amdgcn_mfma_f32_16x16x32_bf16(qf[1][kc], k0, s[1][0], 0, 0, 0);
        s[1][1] = __builtin_amdgcn_mfma_f32_16x16x32_bf16(qf[1][kc], k1, s[1][1], 0, 0, 0);
      }

      // ---- P = exp2(masked S)  (no max, no shuffles) ----
#pragma unroll
      for (int m = 0; m < 2; m++)
#pragma unroll
        for (int i = 0; i < 4; i++) {
          int rg = rbase + m * 16 + q4 * 4 + i;
          float v0 = (t0 + c16 > rg) ? -3.0e38f : s[m][0][i];
          float v1 = (t0 + 16 + c16 > rg) ? -3.0e38f : s[m][1][i];
          pl[wave][m * 16 + q4 * 4 + i][c16] = f2bf(exp2f(v0));
          pl[wave][m * 16 + q4 * 4 + i][16 + c16] = f2bf(exp2f(v1));
        }
      bf16x8 pf0 = *(const bf16x8*)&pl[wave][c16][q4 * 8];
      bf16x8 pf1 = *(const bf16x8*)&pl[wave][16 + c16][q4 * 8];

      // ---- l += P·1, O += P V : each vv fragment feeds BOTH m-tiles ----
      lacc[0] = __builtin_amdgcn_mfma_f32_16x16x32_bf16(pf0, ones, lacc[0], 0, 0, 0);
      lacc[1] = __builtin_amdgcn_mfma_f32_16x16x32_bf16(pf1, ones, lacc[1], 0, 0, 0);
      const unsigned short* vtc = vt[cur];
#pragma unroll
      for (int ct = 0; ct < 32; ct++) {
        bf16x8 vv = *(const bf16x8*)&vtc[(q4 * 512 + ct * 16 + c16) * 8];
        oacc[0][ct] = __builtin_amdgcn_mfma_f32_16x16x32_bf16(pf0, vv, oacc[0][ct], 0, 0, 0);
        oacc[1][ct] = __builtin_amdgcn_mfma_f32_16x16x32_bf16(pf1, vv, oacc[1][ct], 0, 0, 0);
      }
      __syncthreads();   // implicit vmcnt(0): next tile staged; also guards buf reuse
    }

    // ---- epilogue: O /= l, write bf16 (no LDS -> overlaps nothing, runs once/seg) ----
#pragma unroll
    for (int m = 0; m < 2; m++)
#pragma unroll
      for (int i = 0; i < 4; i++) {
        float inv = 1.0f / lacc[m][i];
        unsigned short* dst = opk + (qrow0 + m * 16 + q4 * 4 + i) * 512;
#pragma unroll
        for (int ct = 0; ct < 32; ct++) dst[ct * 16 + c16] = f2bf(oacc[m][ct][i] * inv);
      }
  }
#undef STAGE_KV
}

// ---------------- launch ----------------
extern "C" void kernel_launch(void* const* d_in, const int* in_sizes, int n_in,
                              void* d_out, int out_size, void* d_ws, size_t ws_size,
                              hipStream_t stream) {
  (void)in_sizes; (void)n_in; (void)out_size; (void)ws_size;
  const float* x     = (const float*)d_in[0];
  const float* fc    = (const float*)d_in[1];
  const float* fs    = (const float*)d_in[2];
  const float* wq_a  = (const float*)d_in[4];
  const float* qnw   = (const float*)d_in[5];
  const float* wq_b  = (const float*)d_in[6];
  const float* wkv_a = (const float*)d_in[7];
  const float* kvnw  = (const float*)d_in[8];
  const float* wkv_b = (const float*)d_in[9];
  const float* wo    = (const float*)d_in[10];
  float* out = (float*)d_out;
  char* ws = (char*)d_ws;

  // workspace map (bytes)
  const size_t O_WQA  = 0;           // 1536*2048 bf16
  const size_t O_WQB  = 6291456;     // 3072*1536 bf16
  const size_t O_WKVA = 15728640;    // 640*2048 bf16 (576 valid rows; pad rows read-but-ignored)
  const size_t O_WNT  = 18350080;    // 16*512*128 bf16
  const size_t O_WV   = 20447232;    // 16*128*512 bf16
  const size_t O_WO   = 22544384;    // 2048*2048 bf16
  const size_t O_RA   = 30932992;    // 16.8MB region: x_bf16 -> qnp -> opc
  const size_t O_RB   = 47710208;    // 25.2MB region: q_a_f32 -> q_bf16
  const size_t O_QAN  = 72876032;    // 4096*1536 bf16
  const size_t O_KVF  = 85458944;    // 4096*640 f32
  const size_t O_KVK  = 95944704;    // 2*64*18432 bf16 (K tile prepack, 4.72MB)
  const size_t O_KVT  = 100663296;   // 2*64*16384 bf16 (V^T tile prepack, 4.19MB)
  const size_t O_QCAT = 104857600;   // 16*4096*576 bf16
  const size_t O_OPK  = 180355072;   // 16*4096*512 bf16

  unsigned short* W_QA = (unsigned short*)(ws + O_WQA);
  unsigned short* W_QB = (unsigned short*)(ws + O_WQB);
  unsigned short* W_KVA = (unsigned short*)(ws + O_WKVA);
  unsigned short* W_NT = (unsigned short*)(ws + O_WNT);
  unsigned short* W_V  = (unsigned short*)(ws + O_WV);
  unsigned short* W_O  = (unsigned short*)(ws + O_WO);
  unsigned short* X_B  = (unsigned short*)(ws + O_RA);
  unsigned short* QNP  = (unsigned short*)(ws + O_RA);
  unsigned short* OPC  = (unsigned short*)(ws + O_RA);
  float*          QA_F = (float*)(ws + O_RB);
  unsigned short* QB   = (unsigned short*)(ws + O_RB);
  unsigned short* QAN  = (unsigned short*)(ws + O_QAN);
  float*          KV_F = (float*)(ws + O_KVF);
  unsigned short* KVK  = (unsigned short*)(ws + O_KVK);
  unsigned short* KVT  = (unsigned short*)(ws + O_KVT);
  unsigned short* QCAT = (unsigned short*)(ws + O_QCAT);
  unsigned short* OPK  = (unsigned short*)(ws + O_OPK);

  dim3 blk(256);
  k_f2b<<<dim3(4096), blk, 0, stream>>>(x, X_B, 4096 * 2048);
  k_f2b<<<dim3(1024), blk, 0, stream>>>(wq_a, W_QA, 1536 * 2048);
  k_f2b<<<dim3(1024), blk, 0, stream>>>(wq_b, W_QB, 3072 * 1536);
  k_f2b<<<dim3(1024), blk, 0, stream>>>(wkv_a, W_KVA, 576 * 2048);
  k_f2b<<<dim3(1024), blk, 0, stream>>>(wo, W_O, 2048 * 2048);
  k_wkvb<<<dim3(4096), blk, 0, stream>>>(wkv_b, W_NT, W_V);

  // q_a = x @ wq_a^T (fp32 out), kv = x @ wkv_a^T (fp32 out, N padded to 640)
  k_gemm<0><<<dim3(12, 32, 1), blk, 0, stream>>>(X_B, 2048, 0, W_QA, 2048, 0, QA_F, 1536, 0, 2048);
  k_gemm<0><<<dim3(5, 32, 1), blk, 0, stream>>>(X_B, 2048, 0, W_KVA, 2048, 0, KV_F, 640, 0, 2048);
  k_rms_q<<<dim3(4096), blk, 0, stream>>>(QA_F, qnw, QAN);
  k_prep_kv<<<dim3(4096), blk, 0, stream>>>(KV_F, kvnw, fc, fs, KVK, KVT);
  // q = q_a_n @ wq_b^T (bf16 out; overwrites QA_F region safely)
  k_gemm<1><<<dim3(24, 32, 1), blk, 0, stream>>>(QAN, 1536, 0, W_QB, 1536, 0, QB, 3072, 0, 1536);
  k_repack<<<dim3(1024, 16), blk, 0, stream>>>(QB, fc, fs, QNP, QCAT);
  // q_abs[h] = qnp[h] @ w_nt[h]^T -> qcat cols 0..511
  k_gemm<1><<<dim3(4, 32, 16), blk, 0, stream>>>(QNP, 128, 4096LL * 128, W_NT, 128, 512LL * 128,
                                                 QCAT, 576, 4096LL * 576, 128);
  k_attn<<<dim3(16, 16, 1), blk, 0, stream>>>(QCAT, KVK, KVT, OPK);
  // o_proj[h] = o[h] @ w_v[h]^T -> opc cols h*128..h*128+127
  k_gemm<1><<<dim3(1, 32, 16), blk, 0, stream>>>(OPK, 512, 4096LL * 512, W_V, 512, 128LL * 512,
                                                 OPC, 2048, 128, 512);
  // out = opc @ wo^T (fp32)
  k_gemm<0><<<dim3(16, 32, 1), blk, 0, stream>>>(OPC, 2048, 0, W_O, 2048, 0, out, 2048, 0, 2048);
}

// Round 2
// 692.042 us; speedup vs baseline: 1.0821x; 1.0821x over previous
//
#include <hip/hip_runtime.h>

// ---------------- types / helpers ----------------
typedef __bf16        bf16x8 __attribute__((ext_vector_type(8)));
typedef float         f32x4  __attribute__((ext_vector_type(4)));

typedef unsigned int __attribute__((address_space(1))) as1_u32;
typedef unsigned int __attribute__((address_space(3))) as3_u32;
#define ASYNC16(gp, lp) __builtin_amdgcn_global_load_lds((as1_u32*)(gp), (as3_u32*)(lp), 16, 0, 0)

#define SCALE_F 0.07216878364870323f      /* 192^-0.5 */
#define LOG2E_F 1.4426950408889634f
#define FQ (SCALE_F * LOG2E_F)            /* folded into Q so softmax is exp2 */

static __device__ __forceinline__ unsigned short f2bf(float f) {
  unsigned int u = __builtin_bit_cast(unsigned int, f);
  u += 0x7fff + ((u >> 16) & 1);          // RNE
  return (unsigned short)(u >> 16);
}
static __device__ __forceinline__ float bf2f(unsigned short s) {
  unsigned int u = ((unsigned int)s) << 16;
  return __builtin_bit_cast(float, u);
}

// ---------------- fp32 -> bf16 convert ----------------
__global__ __launch_bounds__(256) void k_f2b(const float* __restrict__ in,
                                             unsigned short* __restrict__ out, int n) {
  int stride = gridDim.x * 256;
  for (int i = blockIdx.x * 256 + threadIdx.x; i < n; i += stride) out[i] = f2bf(in[i]);
}

// wkv_b (16,256,512) -> w_nt[h][c][d] (nope slice transposed) and w_v[h][d][c] (v slice)
__global__ __launch_bounds__(256) void k_wkvb(const float* __restrict__ wkvb,
                                              unsigned short* __restrict__ w_nt,
                                              unsigned short* __restrict__ w_v) {
  int i = blockIdx.x * 256 + threadIdx.x;      // 0 .. 16*512*128-1
  int h = i >> 16;
  int rem = i & 65535;
  int c = rem >> 7, d = rem & 127;             // for w_nt
  w_nt[i] = f2bf(wkvb[((h << 8) + d) * 512 + c]);
  int d2 = rem >> 9, c2 = rem & 511;           // for w_v
  w_v[i] = f2bf(wkvb[((h << 8) + 128 + d2) * 512 + c2]);
}

// ---------------- generic bf16 MFMA GEMM: C[M,N] = A[M,K] @ W[N,K]^T ----------------
// 128x128 tile, BK=32, 256 threads (4 waves, 2x2 of 64x64), global_load_lds staging.
template <int BF16_OUT>
__global__ __launch_bounds__(256) void k_gemm(
    const unsigned short* __restrict__ A, int lda, long long sA,
    const unsigned short* __restrict__ W, int ldw, long long sW,
    void* __restrict__ Cv, int ldc, long long sC, int K) {
  __shared__ unsigned short lA[128 * 32];
  __shared__ unsigned short lW[128 * 32];
  const int tid = threadIdx.x;
  const int lane = tid & 63;
  const int q4 = lane >> 4, c16 = lane & 15;
  const int wave = tid >> 6;
  const int wr = (wave >> 1) * 64, wc = (wave & 1) * 64;
  const int z = blockIdx.z;
  A += (long long)z * sA;
  W += (long long)z * sW;

  f32x4 acc[4][4];
#pragma unroll
  for (int i = 0; i < 4; i++)
#pragma unroll
    for (int j = 0; j < 4; j++) acc[i][j] = (f32x4)0.0f;

  const int r = tid >> 2;
  const int cc = (tid & 3) * 8;
  const unsigned short* gA0 = A + ((long long)blockIdx.y * 128 + r) * lda + cc;
  const unsigned short* gA1 = gA0 + (long long)64 * lda;
  const unsigned short* gW0 = W + ((long long)blockIdx.x * 128 + r) * ldw + cc;
  const unsigned short* gW1 = gW0 + (long long)64 * ldw;
  unsigned short* pA0 = &lA[r * 32 + cc];
  unsigned short* pA1 = &lA[(64 + r) * 32 + cc];
  unsigned short* pW0 = &lW[r * 32 + cc];
  unsigned short* pW1 = &lW[(64 + r) * 32 + cc];

  for (int k0 = 0; k0 < K; k0 += 32) {
    ASYNC16(gA0 + k0, pA0);
    ASYNC16(gA1 + k0, pA1);
    ASYNC16(gW0 + k0, pW0);
    ASYNC16(gW1 + k0, pW1);
    __syncthreads();                       // drains vmcnt -> LDS valid
    bf16x8 af[4], wf[4];
#pragma unroll
    for (int mt = 0; mt < 4; mt++)
      af[mt] = *(const bf16x8*)&lA[(wr + mt * 16 + c16) * 32 + q4 * 8];
#pragma unroll
    for (int nt = 0; nt < 4; nt++)
      wf[nt] = *(const bf16x8*)&lW[(wc + nt * 16 + c16) * 32 + q4 * 8];
#pragma unroll
    for (int mt = 0; mt < 4; mt++)
#pragma unroll
      for (int nt = 0; nt < 4; nt++)
        acc[mt][nt] = __builtin_amdgcn_mfma_f32_16x16x32_bf16(af[mt], wf[nt], acc[mt][nt], 0, 0, 0);
    __syncthreads();
  }

  const long long row0 = (long long)blockIdx.y * 128 + wr + q4 * 4;
  const int col0 = blockIdx.x * 128 + wc + c16;
  if (BF16_OUT) {
    unsigned short* C = (unsigned short*)Cv + (long long)z * sC;
#pragma unroll
    for (int mt = 0; mt < 4; mt++)
#pragma unroll
      for (int i = 0; i < 4; i++) {
        long long rr = (row0 + mt * 16 + i) * (long long)ldc + col0;
#pragma unroll
        for (int nt = 0; nt < 4; nt++) C[rr + nt * 16] = f2bf(acc[mt][nt][i]);
      }
  } else {
    float* C = (float*)Cv + (long long)z * sC;
#pragma unroll
    for (int mt = 0; mt < 4; mt++)
#pragma unroll
      for (int i = 0; i < 4; i++) {
        long long rr = (row0 + mt * 16 + i) * (long long)ldc + col0;
#pragma unroll
        for (int nt = 0; nt < 4; nt++) C[rr + nt * 16] = acc[mt][nt][i];
      }
  }
}

// ---------------- RMSNorm q_a (rows of 1536, fp32 in, bf16 out) ----------------
__global__ __launch_bounds__(256) void k_rms_q(const float* __restrict__ in,
                                               const float* __restrict__ w,
                                               unsigned short* __restrict__ out) {
  const int row = blockIdx.x;
  const int tid = threadIdx.x;
  const float* x = in + (long long)row * 1536;
  float v[6], ss = 0.f;
#pragma unroll
  for (int i = 0; i < 6; i++) { v[i] = x[tid + i * 256]; ss += v[i] * v[i]; }
#pragma unroll
  for (int d = 1; d < 64; d <<= 1) ss += __shfl_xor(ss, d);
  __shared__ float red[4];
  if ((tid & 63) == 0) red[tid >> 6] = ss;
  __syncthreads();
  float sc = rsqrtf((red[0] + red[1] + red[2] + red[3]) * (1.0f / 1536.0f) + 1e-6f);
#pragma unroll
  for (int i = 0; i < 6; i++)
    out[(long long)row * 1536 + tid + i * 256] = f2bf(v[i] * sc * w[tid + i * 256]);
}

// ---------------- kv prep: rmsnorm c(512) + rope k_pe(64) ----------------
// Outputs tile-chunk-major prepacks, contiguous 36KB/32KB per 32-t tile so the
// attention kernel can stage them with perfectly-coalesced global_load_lds:
//   kvk[b][tt][j=0..71][t'=0..31][8]  (row d-chunk major K tile,  18432 elem/tile)
//   kvt[b][tt][q=0..3][c=0..511][8]   (t'-chunk major V^T tile,   16384 elem/tile)
__global__ __launch_bounds__(256) void k_prep_kv(const float* __restrict__ kvf,
                                                 const float* __restrict__ wn,
                                                 const float* __restrict__ fc,
                                                 const float* __restrict__ fs,
                                                 unsigned short* __restrict__ kvk,
                                                 unsigned short* __restrict__ kvt) {
  const int row = blockIdx.x;          // b*2048 + t
  const int tid = threadIdx.x;
  const float* x = kvf + (long long)row * 640;
  float v0 = x[tid], v1 = x[tid + 256];
  float ss = v0 * v0 + v1 * v1;
#pragma unroll
  for (int d = 1; d < 64; d <<= 1) ss += __shfl_xor(ss, d);
  __shared__ float red[4];
  if ((tid & 63) == 0) red[tid >> 6] = ss;
  __syncthreads();
  float sc = rsqrtf((red[0] + red[1] + red[2] + red[3]) * (1.0f / 512.0f) + 1e-6f);
  const int b = row >> 11, t = row & 2047, tt = t >> 5, tl = t & 31;
  float y0 = v0 * sc * wn[tid], y1 = v1 * sc * wn[tid + 256];
  unsigned short* kb = kvk + (long long)(b * 64 + tt) * 18432;
  unsigned short* vb = kvt + (long long)(b * 64 + tt) * 16384;
  const int d0 = tid, d1 = tid + 256;
  kb[((d0 >> 3) * 32 + tl) * 8 + (d0 & 7)] = f2bf(y0);
  kb[((d1 >> 3) * 32 + tl) * 8 + (d1 & 7)] = f2bf(y1);
  vb[((tl >> 3) * 512 + d0) * 8 + (tl & 7)] = f2bf(y0);
  vb[((tl >> 3) * 512 + d1) * 8 + (tl & 7)] = f2bf(y1);
  if (tid < 32) {
    float x0 = x[512 + 2 * tid], x1 = x[513 + 2 * tid];
    float c = fc[t * 32 + tid], s = fs[t * 32 + tid];
    const int e0 = 512 + 2 * tid, e1 = e0 + 1;
    kb[((e0 >> 3) * 32 + tl) * 8 + (e0 & 7)] = f2bf(x0 * c - x1 * s);
    kb[((e1 >> 3) * 32 + tl) * 8 + (e1 & 7)] = f2bf(x0 * s + x1 * c);
  }
}

// ---------------- q repack: q[4096][3072] -> qnp[h][4096][128]*FQ, rope -> qcat[h][.][512:576]*FQ ------
__global__ __launch_bounds__(256) void k_repack(const unsigned short* __restrict__ q,
                                                const float* __restrict__ fc,
                                                const float* __restrict__ fs,
                                                unsigned short* __restrict__ qnp,
                                                unsigned short* __restrict__ qcat) {
  const int h = blockIdx.y;
  const int row = blockIdx.x * 4 + (threadIdx.x >> 6);
  const int ln = threadIdx.x & 63;
  const unsigned short* src = q + (long long)row * 3072 + h * 192;
  unsigned short* dn = qnp + ((long long)h * 4096 + row) * 128;
  dn[ln] = f2bf(bf2f(src[ln]) * FQ);
  dn[ln + 64] = f2bf(bf2f(src[ln + 64]) * FQ);
  if (ln < 32) {
    const int t = row & 2047;
    float x0 = bf2f(src[128 + 2 * ln]), x1 = bf2f(src[129 + 2 * ln]);
    float c = fc[t * 32 + ln], s = fs[t * 32 + ln];
    unsigned short* dc = qcat + ((long long)h * 4096 + row) * 576 + 512;
    dc[2 * ln] = f2bf((x0 * c - x1 * s) * FQ);
    dc[2 * ln + 1] = f2bf((x0 * s + x1 * c) * FQ);
  }
}

// ---------------- flash attention v5: v3 shape (2 blocks/CU) + split-stage pipelining ------
// grid (32 = {b,pair} XCD-packed, 16 heads), 256 threads (4 waves x 16 q-rows = 64-row Q-tile).
// Block processes Q-tiles {p, 31-p} -> 66 T-tiles: balanced.
// v4 post-mortem: M=32/wave forced 1 wave/SIMD (Occupancy 22->11.5%) and regressed 14% --
// the kernel is LATENCY-bound, not LDS-BW-bound; TLP from 2 blocks/CU is worth more than
// halved LDS traffic. v5 keeps v3's M=16 / 72KB-LDS / 128-VGPR shape and instead hides the
// stage drain: K[tt+1] staged right after QK[tt] frees kt (drain covered by softmax+PV),
// V[tt+1] staged right after PV[tt] frees vt (drain covered by next QK). Same 2 barriers
// per tile as v3; the implicit pre-barrier vmcnt(0) now lands >=300cyc after issue.
// Kept from v4: pl stride 40 (2-way max on P reads = free), XCD batch-packing of the grid.
__global__ __launch_bounds__(256, 2) void k_attn(const unsigned short* __restrict__ qcat,
                                                 const unsigned short* __restrict__ kvk,
                                                 const unsigned short* __restrict__ kvt,
                                                 unsigned short* __restrict__ opk) {
  __shared__ __align__(16) unsigned short kt[18432];      // K tile  [j=0..71][t'=0..31][8]
  __shared__ __align__(16) unsigned short vt[16384];      // V^T tile [q=0..3][c=0..511][8]
  __shared__ __align__(16) unsigned short pl[4][16][40];  // per-wave P tile, stride 40
  const int tid = threadIdx.x, lane = tid & 63, wave = tid >> 6;
  const int q4 = lane >> 4, c16 = lane & 15;
  const int bx = blockIdx.x, h = blockIdx.y;
  const int b = (bx >> 2) & 1;                     // bx%8<4 -> b=0 (XCDs 0-3), else b=1
  const int pair = (bx & 3) | ((bx >> 3) << 2);    // 0..15, bijective with b over bx 0..31
  const unsigned short* kvk_b = kvk + (long long)b * 64 * 18432;
  const unsigned short* kvt_b = kvt + (long long)b * 64 * 16384;

  bf16x8 ones;
#pragma unroll
  for (int i = 0; i < 8; i++) ones[i] = (__bf16)1.0f;

#define STAGE_K(tile) do {                                                                   \
    const unsigned short* kg_ = kvk_b + (long long)(tile) * 18432;                           \
    _Pragma("unroll")                                                                        \
    for (int i_ = 0; i_ < 9; i_++) { int ch_ = i_ * 256 + tid; ASYNC16(kg_ + ch_ * 8, &kt[ch_ * 8]); } \
  } while (0)
#define STAGE_V(tile) do {                                                                   \
    const unsigned short* vg_ = kvt_b + (long long)(tile) * 16384;                           \
    _Pragma("unroll")                                                                        \
    for (int i_ = 0; i_ < 8; i_++) { int ch_ = i_ * 256 + tid; ASYNC16(vg_ + ch_ * 8, &vt[ch_ * 8]); } \
  } while (0)

  for (int seg = 0; seg < 2; seg++) {
    const int qt = seg ? (31 - pair) : pair;
    const int s_wave = qt * 64 + wave * 16;
    const long long qrow = (long long)h * 4096 + b * 2048 + s_wave;

    bf16x8 qf[18];
    {
      const unsigned short* qp = qcat + (qrow + c16) * 576 + q4 * 8;
#pragma unroll
      for (int kc = 0; kc < 18; kc++) qf[kc] = *(const bf16x8*)(qp + kc * 32);
    }
    f32x4 oacc[32];
#pragma unroll
    for (int i = 0; i < 32; i++) oacc[i] = (f32x4)0.f;
    f32x4 lacc = (f32x4)0.f;

    const int nT = (qt + 1) * 2;
    STAGE_K(0);
    STAGE_V(0);
    __syncthreads();                       // prologue drain: tile 0 ready

    for (int tt = 0; tt < nT; tt++) {
      const int t0 = tt * 32;

      // ---- S = Q K^T (16x32 per wave), reads kt ----
      f32x4 s0 = (f32x4)0.f, s1 = (f32x4)0.f;
#pragma unroll
      for (int kc = 0; kc < 18; kc++) {
        const unsigned short* kp = &kt[((kc * 4 + q4) * 32 + c16) * 8];
        bf16x8 k0 = *(const bf16x8*)kp;
        bf16x8 k1 = *(const bf16x8*)(kp + 128);
        s0 = __builtin_amdgcn_mfma_f32_16x16x32_bf16(qf[kc], k0, s0, 0, 0, 0);
        s1 = __builtin_amdgcn_mfma_f32_16x16x32_bf16(qf[kc], k1, s1, 0, 0, 0);
      }
      __syncthreads();                     // all waves done reading kt
      if (tt + 1 < nT) STAGE_K(tt + 1);    // issue-early; drained at NEXT barrier (PV cover)

      // ---- P = exp2(masked S)  (no max, no shuffles; pl is wave-private) ----
#pragma unroll
      for (int i = 0; i < 4; i++) {
        int s_g = s_wave + q4 * 4 + i;
        float v0 = (t0 + c16 > s_g) ? -3.0e38f : s0[i];
        float v1 = (t0 + 16 + c16 > s_g) ? -3.0e38f : s1[i];
        pl[wave][q4 * 4 + i][c16] = f2bf(exp2f(v0));
        pl[wave][q4 * 4 + i][16 + c16] = f2bf(exp2f(v1));
      }
      bf16x8 pf = *(const bf16x8*)&pl[wave][c16][q4 * 8];

      // ---- l += P·1 (one MFMA), O += P V : reads vt ----
      lacc = __builtin_amdgcn_mfma_f32_16x16x32_bf16(pf, ones, lacc, 0, 0, 0);
#pragma unroll
      for (int ct = 0; ct < 32; ct++) {
        bf16x8 vv = *(const bf16x8*)&vt[(q4 * 512 + ct * 16 + c16) * 8];
        oacc[ct] = __builtin_amdgcn_mfma_f32_16x16x32_bf16(pf, vv, oacc[ct], 0, 0, 0);
      }
      __syncthreads();                     // all waves done reading vt; drains K[tt+1] stage
      if (tt + 1 < nT) STAGE_V(tt + 1);    // issue-early; drained at next-iter barrier (QK cover)
    }

    // ---- epilogue: O /= l, write bf16 (global only, no LDS hazard vs next seg's stages) ----
    const long long orow = qrow + q4 * 4;
#pragma unroll
    for (int i = 0; i < 4; i++) {
      float inv = 1.0f / lacc[i];
      unsigned short* dst = opk + (orow + i) * 512;
#pragma unroll
      for (int ct = 0; ct < 32; ct++) dst[ct * 16 + c16] = f2bf(oacc[ct][i] * inv);
    }
  }
#undef STAGE_K
#undef STAGE_V
}

// ---------------- launch ----------------
extern "C" void kernel_launch(void* const* d_in, const int* in_sizes, int n_in,
                              void* d_out, int out_size, void* d_ws, size_t ws_size,
                              hipStream_t stream) {
  (void)in_sizes; (void)n_in; (void)out_size; (void)ws_size;
  const float* x     = (const float*)d_in[0];
  const float* fc    = (const float*)d_in[1];
  const float* fs    = (const float*)d_in[2];
  const float* wq_a  = (const float*)d_in[4];
  const float* qnw   = (const float*)d_in[5];
  const float* wq_b  = (const float*)d_in[6];
  const float* wkv_a = (const float*)d_in[7];
  const float* kvnw  = (const float*)d_in[8];
  const float* wkv_b = (const float*)d_in[9];
  const float* wo    = (const float*)d_in[10];
  float* out = (float*)d_out;
  char* ws = (char*)d_ws;

  // workspace map (bytes)
  const size_t O_WQA  = 0;           // 1536*2048 bf16
  const size_t O_WQB  = 6291456;     // 3072*1536 bf16
  const size_t O_WKVA = 15728640;    // 640*2048 bf16 (576 valid rows; pad rows read-but-ignored)
  const size_t O_WNT  = 18350080;    // 16*512*128 bf16
  const size_t O_WV   = 20447232;    // 16*128*512 bf16
  const size_t O_WO   = 22544384;    // 2048*2048 bf16
  const size_t O_RA   = 30932992;    // 16.8MB region: x_bf16 -> qnp -> opc
  const size_t O_RB   = 47710208;    // 25.2MB region: q_a_f32 -> q_bf16
  const size_t O_QAN  = 72876032;    // 4096*1536 bf16
  const size_t O_KVF  = 85458944;    // 4096*640 f32
  const size_t O_KVK  = 95944704;    // 2*64*18432 bf16 (K tile prepack, 4.72MB)
  const size_t O_KVT  = 100663296;   // 2*64*16384 bf16 (V^T tile prepack, 4.19MB)
  const size_t O_QCAT = 104857600;   // 16*4096*576 bf16
  const size_t O_OPK  = 180355072;   // 16*4096*512 bf16

  unsigned short* W_QA = (unsigned short*)(ws + O_WQA);
  unsigned short* W_QB = (unsigned short*)(ws + O_WQB);
  unsigned short* W_KVA = (unsigned short*)(ws + O_WKVA);
  unsigned short* W_NT = (unsigned short*)(ws + O_WNT);
  unsigned short* W_V  = (unsigned short*)(ws + O_WV);
  unsigned short* W_O  = (unsigned short*)(ws + O_WO);
  unsigned short* X_B  = (unsigned short*)(ws + O_RA);
  unsigned short* QNP  = (unsigned short*)(ws + O_RA);
  unsigned short* OPC  = (unsigned short*)(ws + O_RA);
  float*          QA_F = (float*)(ws + O_RB);
  unsigned short* QB   = (unsigned short*)(ws + O_RB);
  unsigned short* QAN  = (unsigned short*)(ws + O_QAN);
  float*          KV_F = (float*)(ws + O_KVF);
  unsigned short* KVK  = (unsigned short*)(ws + O_KVK);
  unsigned short* KVT  = (unsigned short*)(ws + O_KVT);
  unsigned short* QCAT = (unsigned short*)(ws + O_QCAT);
  unsigned short* OPK  = (unsigned short*)(ws + O_OPK);

  dim3 blk(256);
  k_f2b<<<dim3(4096), blk, 0, stream>>>(x, X_B, 4096 * 2048);
  k_f2b<<<dim3(1024), blk, 0, stream>>>(wq_a, W_QA, 1536 * 2048);
  k_f2b<<<dim3(1024), blk, 0, stream>>>(wq_b, W_QB, 3072 * 1536);
  k_f2b<<<dim3(1024), blk, 0, stream>>>(wkv_a, W_KVA, 576 * 2048);
  k_f2b<<<dim3(1024), blk, 0, stream>>>(wo, W_O, 2048 * 2048);
  k_wkvb<<<dim3(4096), blk, 0, stream>>>(wkv_b, W_NT, W_V);

  // q_a = x @ wq_a^T (fp32 out), kv = x @ wkv_a^T (fp32 out, N padded to 640)
  k_gemm<0><<<dim3(12, 32, 1), blk, 0, stream>>>(X_B, 2048, 0, W_QA, 2048, 0, QA_F, 1536, 0, 2048);
  k_gemm<0><<<dim3(5, 32, 1), blk, 0, stream>>>(X_B, 2048, 0, W_KVA, 2048, 0, KV_F, 640, 0, 2048);
  k_rms_q<<<dim3(4096), blk, 0, stream>>>(QA_F, qnw, QAN);
  k_prep_kv<<<dim3(4096), blk, 0, stream>>>(KV_F, kvnw, fc, fs, KVK, KVT);
  // q = q_a_n @ wq_b^T (bf16 out; overwrites QA_F region safely)
  k_gemm<1><<<dim3(24, 32, 1), blk, 0, stream>>>(QAN, 1536, 0, W_QB, 1536, 0, QB, 3072, 0, 1536);
  k_repack<<<dim3(1024, 16), blk, 0, stream>>>(QB, fc, fs, QNP, QCAT);
  // q_abs[h] = qnp[h] @ w_nt[h]^T -> qcat cols 0..511
  k_gemm<1><<<dim3(4, 32, 16), blk, 0, stream>>>(QNP, 128, 4096LL * 128, W_NT, 128, 512LL * 128,
                                                 QCAT, 576, 4096LL * 576, 128);
  k_attn<<<dim3(32, 16, 1), blk, 0, stream>>>(QCAT, KVK, KVT, OPK);
  // o_proj[h] = o[h] @ w_v[h]^T -> opc cols h*128..h*128+127
  k_gemm<1><<<dim3(1, 32, 16), blk, 0, stream>>>(OPK, 512, 4096LL * 512, W_V, 512, 128LL * 512,
                                                 OPC, 2048, 128, 512);
  // out = opc @ wo^T (fp32)
  k_gemm<0><<<dim3(16, 32, 1), blk, 0, stream>>>(OPC, 2048, 0, W_O, 2048, 0, out, 2048, 0, 2048);
}